// Round 1
// baseline (571.333 us; speedup 1.0000x reference)
//
#include <hip/hip_runtime.h>

#define B_ 256
#define N_ 64
#define T_ 4096
#define H_ 16

// ---------- Kernel A: per-(b,n) variance over T ----------
__global__ __launch_bounds__(256) void k_var(const float* __restrict__ x,
                                             float* __restrict__ energy) {
  const int row = blockIdx.x;                 // b*N + n
  const float* __restrict__ xr = x + (size_t)row * T_;
  const int tid = threadIdx.x;
  float s = 0.f, ss = 0.f;
#pragma unroll
  for (int k = 0; k < 4; ++k) {
    const float4 v = *(const float4*)(xr + (k * 256 + tid) * 4);
    s  += v.x + v.y + v.z + v.w;
    ss += v.x * v.x + v.y * v.y + v.z * v.z + v.w * v.w;
  }
#pragma unroll
  for (int off = 32; off > 0; off >>= 1) {
    s  += __shfl_down(s, off, 64);
    ss += __shfl_down(ss, off, 64);
  }
  __shared__ float sh[8];
  const int wid = tid >> 6;
  if ((tid & 63) == 0) { sh[wid] = s; sh[4 + wid] = ss; }
  __syncthreads();
  if (tid == 0) {
    const float S  = sh[0] + sh[1] + sh[2] + sh[3];
    const float SS = sh[4] + sh[5] + sh[6] + sh[7];
    const float m  = S * (1.0f / T_);
    energy[row] = SS * (1.0f / T_) - m * m;
  }
}

// ---------- Kernel B: analytic softmax attention weights ----------
// logit[b,i,j] = 0.25*(c1*e_i*e_j + c2*e_i + c3*e_j + c4); row-constant terms
// cancel under softmax -> logit = beta_i * e_j with beta_i = 0.25*(c1*e_i + c3).
// Diagonal mask -1e9 underflows to exp()==0 in fp32, so set weight 0 exactly.
__global__ __launch_bounds__(64) void k_attn(const float* __restrict__ energy,
                                             const float* __restrict__ Wq,
                                             const float* __restrict__ bq,
                                             const float* __restrict__ Wk,
                                             const float* __restrict__ bk,
                                             float* __restrict__ attn) {
  const int b = blockIdx.x;
  const int i = threadIdx.x;                  // 0..63 (one wave)
  __shared__ float e[N_];
  __shared__ float wrow[N_][N_ + 1];
  e[i] = energy[b * N_ + i];
  float c1 = 0.f, c3 = 0.f;
#pragma unroll
  for (int h = 0; h < H_; ++h) { c1 += Wq[h] * Wk[h]; c3 += bq[h] * Wk[h]; }
  __syncthreads();
  const float beta = 0.25f * (c1 * e[i] + c3);   // scale = H^-0.5 = 0.25
  float l[N_];
  float mx = -3.0e38f;
#pragma unroll
  for (int j = 0; j < N_; ++j) {
    float lj = beta * e[j];
    if (j == i) lj = -3.0e38f;
    l[j] = lj;
    mx = fmaxf(mx, lj);
  }
  float sum = 0.f;
#pragma unroll
  for (int j = 0; j < N_; ++j) {
    float ex = (j == i) ? 0.f : __expf(l[j] - mx);
    l[j] = ex;
    sum += ex;
  }
  const float inv = 1.0f / sum;
#pragma unroll
  for (int j = 0; j < N_; ++j) wrow[i][j] = l[j] * inv;
  __syncthreads();
  float* __restrict__ ab = attn + (size_t)b * (N_ * N_);
#pragma unroll
  for (int r = 0; r < N_; ++r) ab[r * N_ + i] = wrow[r][i];
}

// ---------- Kernel C: out[b,i,t] = x[b,i,t] + sum_j w[b,i,j]*x[b,j,t] ----------
__device__ __forceinline__ void fma4(float4& a, float w, const float4& v) {
  a.x = fmaf(w, v.x, a.x);
  a.y = fmaf(w, v.y, a.y);
  a.z = fmaf(w, v.z, a.z);
  a.w = fmaf(w, v.w, a.w);
}

__global__ __launch_bounds__(256) void k_out(const float* __restrict__ x,
                                             const float* __restrict__ attn,
                                             float* __restrict__ out) {
  const int b  = blockIdx.x >> 4;
  const int tt = blockIdx.x & 15;             // 16 tiles of 256 t-columns
  const int tid  = threadIdx.x;
  const int lane = tid & 63;
  const int warp = tid >> 6;                  // i-range [16*warp, 16*warp+16)

  __shared__ float wt[N_ * N_];               // transposed: wt[j*64 + i]
  const float* __restrict__ ab = attn + (size_t)b * (N_ * N_);
#pragma unroll
  for (int k = 0; k < 4; ++k) {
    const int f4 = k * 256 + tid;             // float4 index 0..1023
    const float4 v = *(const float4*)(ab + f4 * 4);
    const int i = (f4 * 4) >> 6;
    const int j = (f4 * 4) & 63;
    wt[(j + 0) * N_ + i] = v.x;
    wt[(j + 1) * N_ + i] = v.y;
    wt[(j + 2) * N_ + i] = v.z;
    wt[(j + 3) * N_ + i] = v.w;
  }
  __syncthreads();

  const int ibase = warp << 4;
  const float* __restrict__ xb = x + (size_t)b * (N_ * T_) + tt * 256 + lane * 4;

  float4 acc[16];
#pragma unroll
  for (int ii = 0; ii < 16; ++ii) acc[ii] = make_float4(0.f, 0.f, 0.f, 0.f);

#pragma unroll 8
  for (int j = 0; j < N_; ++j) {
    const float4 xv = *(const float4*)(xb + (size_t)j * T_);
    const float4* __restrict__ wj = (const float4*)(wt + j * N_ + ibase);
    const float4 w0 = wj[0], w1 = wj[1], w2 = wj[2], w3 = wj[3];
    fma4(acc[0],  w0.x, xv); fma4(acc[1],  w0.y, xv);
    fma4(acc[2],  w0.z, xv); fma4(acc[3],  w0.w, xv);
    fma4(acc[4],  w1.x, xv); fma4(acc[5],  w1.y, xv);
    fma4(acc[6],  w1.z, xv); fma4(acc[7],  w1.w, xv);
    fma4(acc[8],  w2.x, xv); fma4(acc[9],  w2.y, xv);
    fma4(acc[10], w2.z, xv); fma4(acc[11], w2.w, xv);
    fma4(acc[12], w3.x, xv); fma4(acc[13], w3.y, xv);
    fma4(acc[14], w3.z, xv); fma4(acc[15], w3.w, xv);
  }

  float* __restrict__ ob = out + (size_t)b * (N_ * T_) + tt * 256 + lane * 4;
#pragma unroll
  for (int ii = 0; ii < 16; ++ii) {
    const int i = ibase + ii;
    const float4 xo = *(const float4*)(xb + (size_t)i * T_);
    float4 r;
    r.x = acc[ii].x + xo.x;
    r.y = acc[ii].y + xo.y;
    r.z = acc[ii].z + xo.z;
    r.w = acc[ii].w + xo.w;
    *(float4*)(ob + (size_t)i * T_) = r;
  }
}

extern "C" void kernel_launch(void* const* d_in, const int* in_sizes, int n_in,
                              void* d_out, int out_size, void* d_ws, size_t ws_size,
                              hipStream_t stream) {
  const float* x  = (const float*)d_in[0];
  const float* Wq = (const float*)d_in[1];
  const float* bq = (const float*)d_in[2];
  const float* Wk = (const float*)d_in[3];
  const float* bk = (const float*)d_in[4];
  float* out  = (float*)d_out;
  float* attn = out + (size_t)B_ * N_ * T_;
  // Stash energy in the out region (overwritten later by k_out) to avoid
  // assuming anything about ws_size. Stream order guarantees correctness.
  float* energy = out;
  hipLaunchKernelGGL(k_var, dim3(B_ * N_), dim3(256), 0, stream, x, energy);
  hipLaunchKernelGGL(k_attn, dim3(B_), dim3(64), 0, stream,
                     energy, Wq, bq, Wk, bk, attn);
  hipLaunchKernelGGL(k_out, dim3(B_ * 16), dim3(256), 0, stream, x, attn, out);
}